// Round 4
// baseline (346.416 us; speedup 1.0000x reference)
//
#include <hip/hip_runtime.h>
#include <hip/hip_bf16.h>

#define T_TOK 4096
#define DDIM  768
#define IDIM  2048
#define NEXP  8

typedef __attribute__((ext_vector_type(8))) short  bfrag;   // 8 bf16 = 4 VGPR
typedef __attribute__((ext_vector_type(4))) float  ffrag;   // 4 f32 acc

static __device__ __forceinline__ unsigned short f2bf(float f) {
    union { float f; unsigned u; } v; v.f = f;
    unsigned r = v.u + 0x7FFFu + ((v.u >> 16) & 1u);   // RNE
    return (unsigned short)(r >> 16);
}

static __device__ __forceinline__ unsigned cvt2(float x, float y) {
    return (unsigned)f2bf(x) | ((unsigned)f2bf(y) << 16);
}

// ws int layout: counts[8] @0, offsets[9] @16
// fused histogram + scan + permute; ballot-aggregated atomics (8/wave not 64)
__global__ void k_sort(const int* __restrict__ pos, int* __restrict__ ws_i,
                       int* __restrict__ perm) {
    __shared__ int hist[NEXP], cursor[NEXP];
    const int tid  = threadIdx.x;
    const int lane = tid & 63;
    if (tid < NEXP) hist[tid] = 0;
    __syncthreads();
    for (int i = tid; i < T_TOK; i += 1024) {
        int e = pos[i];
        #pragma unroll
        for (int ee = 0; ee < NEXP; ++ee) {
            unsigned long long m = __ballot(e == ee);
            if (e == ee && lane == (__ffsll((long long)m) - 1))
                atomicAdd(&hist[ee], __popcll(m));
        }
    }
    __syncthreads();
    if (tid == 0) {
        int s = 0;
        for (int e = 0; e < NEXP; ++e) {
            cursor[e] = s;
            ws_i[e] = hist[e];
            ws_i[16 + e] = s;
            s += hist[e];
        }
        ws_i[16 + NEXP] = s;
    }
    __syncthreads();
    for (int i = tid; i < T_TOK; i += 1024) {
        int e = pos[i];
        int p = 0;
        #pragma unroll
        for (int ee = 0; ee < NEXP; ++ee) {
            unsigned long long m = __ballot(e == ee);
            if (e == ee) {
                int leader = __ffsll((long long)m) - 1;
                int rank = __popcll(m & ((1ull << lane) - 1ull));
                int base = 0;
                if (lane == leader) base = atomicAdd(&cursor[ee], __popcll(m));
                base = __shfl(base, leader);
                p = base + rank;
            }
        }
        perm[p] = i;
    }
}

// gather + fp32->bf16: one block per gathered row
__global__ void k_gather(const float* __restrict__ x, const int* __restrict__ perm,
                         unsigned short* __restrict__ xg) {
    int p = blockIdx.x;
    int tok = perm[p];
    int j = threadIdx.x * 4;
    const float4 v = *reinterpret_cast<const float4*>(x + (size_t)tok * DDIM + j);
    uint2 o;
    o.x = cvt2(v.x, v.y);
    o.y = cvt2(v.z, v.w);
    *reinterpret_cast<uint2*>(xg + (size_t)p * DDIM + j) = o;
}

// GEMM1: xg[cnt x 768] bf16 @ gate/up^T -> h = silu(g)*u, bf16
// block = (n-tile of 64, m-group, expert); m-tiles looped INSIDE the block so
// the weight slab is fetched ~once from HBM (m-group partner shares via L2:
// partner block id differs by gridDim.x=32 == 0 mod 8 -> same XCD heuristic)
__launch_bounds__(256, 2)
__global__ void k_gemm1(const unsigned short* __restrict__ xg,
                        const float* __restrict__ gate_w,
                        const float* __restrict__ up_w,
                        unsigned short* __restrict__ hg,
                        const int* __restrict__ ws_i) {
    const int e   = blockIdx.z;
    const int cnt = ws_i[e];
    if (cnt == 0) return;
    const int nmt = (cnt + 127) >> 7;
    const int mg  = blockIdx.y;               // 0..1, m-tiles mg, mg+2, ...
    if (mg >= nmt) return;
    const int off = ws_i[16 + e];
    const int n0  = blockIdx.x * 64;

    const int tid  = threadIdx.x;
    const int lane = tid & 63;
    const int wave = tid >> 6;
    const int wm   = wave & 1;
    const int wn   = wave >> 1;

    __shared__ __align__(16) unsigned short lsA[128 * 56];
    __shared__ __align__(16) unsigned short lsG[64 * 56];
    __shared__ __align__(16) unsigned short lsU[64 * 56];

    const float* gate_e = gate_w + (size_t)e * (IDIM * DDIM);
    const float* up_e   = up_w   + (size_t)e * (IDIM * DDIM);

    const int ar = tid >> 2;      // A rows 0..63 (+64)
    const int aq = tid & 3;
    const int br = tid >> 3;      // B rows 0..31 (+32)
    const int bq = tid & 7;

    const float* gp0 = gate_e + (size_t)(n0 + br)      * DDIM + bq * 4;
    const float* gp1 = gate_e + (size_t)(n0 + br + 32) * DDIM + bq * 4;
    const float* up0 = up_e   + (size_t)(n0 + br)      * DDIM + bq * 4;
    const float* up1 = up_e   + (size_t)(n0 + br + 32) * DDIM + bq * 4;

    const int koff = (lane >> 4) * 8;
    const int rsel = lane & 15;
    const int colb  = lane & 15;
    const int rquad = (lane >> 4) * 4;

    for (int mt = mg; mt < nmt; mt += 2) {
        const int m0 = mt * 128;
        int g0 = off + m0 + ar;      if (g0 > T_TOK - 1) g0 = T_TOK - 1;
        int g1 = off + m0 + ar + 64; if (g1 > T_TOK - 1) g1 = T_TOK - 1;
        const unsigned short* a0p = xg + (size_t)g0 * DDIM + aq * 8;
        const unsigned short* a1p = xg + (size_t)g1 * DDIM + aq * 8;

        uint4  pa0 = *reinterpret_cast<const uint4*>(a0p);
        uint4  pa1 = *reinterpret_cast<const uint4*>(a1p);
        float4 pg0 = *reinterpret_cast<const float4*>(gp0);
        float4 pg1 = *reinterpret_cast<const float4*>(gp1);
        float4 pu0 = *reinterpret_cast<const float4*>(up0);
        float4 pu1 = *reinterpret_cast<const float4*>(up1);

        ffrag accG[4][2], accU[4][2];
        const ffrag fz = {0.f, 0.f, 0.f, 0.f};
        #pragma unroll
        for (int mi = 0; mi < 4; ++mi)
            #pragma unroll
            for (int ni = 0; ni < 2; ++ni) { accG[mi][ni] = fz; accU[mi][ni] = fz; }

        for (int kt = 0; kt < DDIM / 32; ++kt) {
            *reinterpret_cast<uint4*>(&lsA[ar * 56 + aq * 8])        = pa0;
            *reinterpret_cast<uint4*>(&lsA[(ar + 64) * 56 + aq * 8]) = pa1;
            { uint2 o; o.x = cvt2(pg0.x, pg0.y); o.y = cvt2(pg0.z, pg0.w);
              *reinterpret_cast<uint2*>(&lsG[br * 56 + bq * 4]) = o; }
            { uint2 o; o.x = cvt2(pg1.x, pg1.y); o.y = cvt2(pg1.z, pg1.w);
              *reinterpret_cast<uint2*>(&lsG[(br + 32) * 56 + bq * 4]) = o; }
            { uint2 o; o.x = cvt2(pu0.x, pu0.y); o.y = cvt2(pu0.z, pu0.w);
              *reinterpret_cast<uint2*>(&lsU[br * 56 + bq * 4]) = o; }
            { uint2 o; o.x = cvt2(pu1.x, pu1.y); o.y = cvt2(pu1.z, pu1.w);
              *reinterpret_cast<uint2*>(&lsU[(br + 32) * 56 + bq * 4]) = o; }
            __syncthreads();

            if (kt < DDIM / 32 - 1) {
                const int kb = (kt + 1) * 32;
                pa0 = *reinterpret_cast<const uint4*>(a0p + kb);
                pa1 = *reinterpret_cast<const uint4*>(a1p + kb);
                pg0 = *reinterpret_cast<const float4*>(gp0 + kb);
                pg1 = *reinterpret_cast<const float4*>(gp1 + kb);
                pu0 = *reinterpret_cast<const float4*>(up0 + kb);
                pu1 = *reinterpret_cast<const float4*>(up1 + kb);
            }

            bfrag a[4], bg[2], bu[2];
            #pragma unroll
            for (int mi = 0; mi < 4; ++mi)
                a[mi] = *reinterpret_cast<const bfrag*>(&lsA[(wm * 64 + mi * 16 + rsel) * 56 + koff]);
            #pragma unroll
            for (int ni = 0; ni < 2; ++ni) {
                bg[ni] = *reinterpret_cast<const bfrag*>(&lsG[(wn * 32 + ni * 16 + rsel) * 56 + koff]);
                bu[ni] = *reinterpret_cast<const bfrag*>(&lsU[(wn * 32 + ni * 16 + rsel) * 56 + koff]);
            }
            #pragma unroll
            for (int mi = 0; mi < 4; ++mi)
                #pragma unroll
                for (int ni = 0; ni < 2; ++ni) {
                    accG[mi][ni] = __builtin_amdgcn_mfma_f32_16x16x32_bf16(a[mi], bg[ni], accG[mi][ni], 0, 0, 0);
                    accU[mi][ni] = __builtin_amdgcn_mfma_f32_16x16x32_bf16(a[mi], bu[ni], accU[mi][ni], 0, 0, 0);
                }
            __syncthreads();
        }

        #pragma unroll
        for (int mi = 0; mi < 4; ++mi)
            #pragma unroll
            for (int ni = 0; ni < 2; ++ni) {
                int n = n0 + wn * 32 + ni * 16 + colb;
                #pragma unroll
                for (int r = 0; r < 4; ++r) {
                    int ml = wm * 64 + mi * 16 + rquad + r;
                    if (m0 + ml < cnt) {
                        float g = accG[mi][ni][r];
                        float u = accU[mi][ni][r];
                        float h = (g / (1.0f + __expf(-g))) * u;
                        hg[(size_t)(off + m0 + ml) * IDIM + n] = f2bf(h);
                    }
                }
            }
    }
}

// GEMM2: hg[cnt x 2048] bf16 @ down^T -> out (fp32), scatter rows via perm.
// Full K per block (no split-K): each output element written once -> plain
// stores, no memset. m-tiles looped inside; 4 m-group blocks share the weight
// slab (ids differ by 12*8=96 == 0 mod 8 -> same XCD).
__launch_bounds__(256, 2)
__global__ void k_gemm2(const unsigned short* __restrict__ hg,
                        const float* __restrict__ down_w,
                        float* __restrict__ out,
                        const int* __restrict__ ws_i,
                        const int* __restrict__ perm) {
    const int e   = blockIdx.y;
    const int cnt = ws_i[e];
    if (cnt == 0) return;
    const int nmt = (cnt + 127) >> 7;
    const int mg  = blockIdx.z;               // 0..3
    if (mg >= nmt) return;
    const int off = ws_i[16 + e];
    const int n0  = blockIdx.x * 64;

    const int tid  = threadIdx.x;
    const int lane = tid & 63;
    const int wave = tid >> 6;
    const int wm   = wave & 1;
    const int wn   = wave >> 1;

    __shared__ __align__(16) unsigned short lsA[128 * 56];
    __shared__ __align__(16) unsigned short lsB[64 * 56];

    const float* down_e = down_w + (size_t)e * (DDIM * IDIM);

    const int ar = tid >> 2;
    const int aq = tid & 3;
    const int br = tid >> 3;
    const int bq = tid & 7;

    const float* bp0 = down_e + (size_t)(n0 + br)      * IDIM + bq * 4;
    const float* bp1 = down_e + (size_t)(n0 + br + 32) * IDIM + bq * 4;

    const int koff = (lane >> 4) * 8;
    const int rsel = lane & 15;
    const int colb  = lane & 15;
    const int rquad = (lane >> 4) * 4;

    for (int mt = mg; mt < nmt; mt += 4) {
        const int m0 = mt * 128;
        int g0 = off + m0 + ar;      if (g0 > T_TOK - 1) g0 = T_TOK - 1;
        int g1 = off + m0 + ar + 64; if (g1 > T_TOK - 1) g1 = T_TOK - 1;
        const unsigned short* a0p = hg + (size_t)g0 * IDIM + aq * 8;
        const unsigned short* a1p = hg + (size_t)g1 * IDIM + aq * 8;

        uint4  pa0 = *reinterpret_cast<const uint4*>(a0p);
        uint4  pa1 = *reinterpret_cast<const uint4*>(a1p);
        float4 pb0 = *reinterpret_cast<const float4*>(bp0);
        float4 pb1 = *reinterpret_cast<const float4*>(bp1);

        ffrag acc[4][2];
        const ffrag fz = {0.f, 0.f, 0.f, 0.f};
        #pragma unroll
        for (int mi = 0; mi < 4; ++mi)
            #pragma unroll
            for (int ni = 0; ni < 2; ++ni) acc[mi][ni] = fz;

        for (int kt = 0; kt < IDIM / 32; ++kt) {
            *reinterpret_cast<uint4*>(&lsA[ar * 56 + aq * 8])        = pa0;
            *reinterpret_cast<uint4*>(&lsA[(ar + 64) * 56 + aq * 8]) = pa1;
            { uint2 o; o.x = cvt2(pb0.x, pb0.y); o.y = cvt2(pb0.z, pb0.w);
              *reinterpret_cast<uint2*>(&lsB[br * 56 + bq * 4]) = o; }
            { uint2 o; o.x = cvt2(pb1.x, pb1.y); o.y = cvt2(pb1.z, pb1.w);
              *reinterpret_cast<uint2*>(&lsB[(br + 32) * 56 + bq * 4]) = o; }
            __syncthreads();

            if (kt < IDIM / 32 - 1) {
                const int kb = (kt + 1) * 32;
                pa0 = *reinterpret_cast<const uint4*>(a0p + kb);
                pa1 = *reinterpret_cast<const uint4*>(a1p + kb);
                pb0 = *reinterpret_cast<const float4*>(bp0 + kb);
                pb1 = *reinterpret_cast<const float4*>(bp1 + kb);
            }

            bfrag a[4], b[2];
            #pragma unroll
            for (int mi = 0; mi < 4; ++mi)
                a[mi] = *reinterpret_cast<const bfrag*>(&lsA[(wm * 64 + mi * 16 + rsel) * 56 + koff]);
            #pragma unroll
            for (int ni = 0; ni < 2; ++ni)
                b[ni] = *reinterpret_cast<const bfrag*>(&lsB[(wn * 32 + ni * 16 + rsel) * 56 + koff]);
            #pragma unroll
            for (int mi = 0; mi < 4; ++mi)
                #pragma unroll
                for (int ni = 0; ni < 2; ++ni)
                    acc[mi][ni] = __builtin_amdgcn_mfma_f32_16x16x32_bf16(a[mi], b[ni], acc[mi][ni], 0, 0, 0);
            __syncthreads();
        }

        #pragma unroll
        for (int mi = 0; mi < 4; ++mi)
            #pragma unroll
            for (int r = 0; r < 4; ++r) {
                int ml = wm * 64 + mi * 16 + rquad + r;
                if (m0 + ml < cnt) {
                    int tok = perm[off + m0 + ml];
                    float* orow = out + (size_t)tok * DDIM + n0 + wn * 32 + colb;
                    orow[0]  = acc[mi][0][r];
                    orow[16] = acc[mi][1][r];
                }
            }
    }
}

extern "C" void kernel_launch(void* const* d_in, const int* in_sizes, int n_in,
                              void* d_out, int out_size, void* d_ws, size_t ws_size,
                              hipStream_t stream) {
    const float* x      = (const float*)d_in[0];
    const int*   pos    = (const int*)d_in[1];
    const float* gate_w = (const float*)d_in[3];
    const float* up_w   = (const float*)d_in[4];
    const float* down_w = (const float*)d_in[5];
    float* out = (float*)d_out;

    char* ws = (char*)d_ws;
    int* ws_i = (int*)ws;
    int* perm = (int*)(ws + 1024);
    unsigned short* xg = (unsigned short*)(ws + 32768);      // 6.3 MB bf16
    unsigned short* hg = (unsigned short*)(ws + (8u << 20)); // 16.8 MB bf16

    k_sort<<<dim3(1), dim3(1024), 0, stream>>>(pos, ws_i, perm);
    k_gather<<<dim3(T_TOK), dim3(192), 0, stream>>>(x, perm, xg);

    dim3 g1(IDIM / 64, 2, NEXP);      // (n-tile, m-group, expert) = 512 blocks
    k_gemm1<<<g1, dim3(256), 0, stream>>>(xg, gate_w, up_w, hg, ws_i);
    dim3 g2(DDIM / 64, NEXP, 4);      // (n-tile, expert, m-group) = 384 blocks
    k_gemm2<<<g2, dim3(256), 0, stream>>>(hg, down_w, out, ws_i, perm);
}

// Round 5
// 327.332 us; speedup vs baseline: 1.0583x; 1.0583x over previous
//
#include <hip/hip_runtime.h>
#include <hip/hip_bf16.h>

#define T_TOK 4096
#define DDIM  768
#define IDIM  2048
#define NEXP  8

typedef __attribute__((ext_vector_type(8))) short  bfrag;   // 8 bf16 = 4 VGPR
typedef __attribute__((ext_vector_type(4))) float  ffrag;   // 4 f32 acc

static __device__ __forceinline__ unsigned short f2bf(float f) {
    union { float f; unsigned u; } v; v.f = f;
    unsigned r = v.u + 0x7FFFu + ((v.u >> 16) & 1u);   // RNE
    return (unsigned short)(r >> 16);
}

static __device__ __forceinline__ unsigned cvt2(float x, float y) {
    return (unsigned)f2bf(x) | ((unsigned)f2bf(y) << 16);
}

// async global->LDS, 16B per lane; LDS dst must be wave-uniform base + lane*16
#define GL2LDS(gp, lp) __builtin_amdgcn_global_load_lds(                      \
    (const __attribute__((address_space(1))) void*)(const void*)(gp),          \
    (__attribute__((address_space(3))) void*)(lp), 16, 0, 0)

// ws int layout: counts[8] @0, offsets[9] @16
__global__ void k_sort(const int* __restrict__ pos, int* __restrict__ ws_i,
                       int* __restrict__ perm) {
    __shared__ int hist[NEXP], cursor[NEXP];
    const int tid  = threadIdx.x;
    const int lane = tid & 63;
    if (tid < NEXP) hist[tid] = 0;
    __syncthreads();
    for (int i = tid; i < T_TOK; i += 1024) {
        int e = pos[i];
        #pragma unroll
        for (int ee = 0; ee < NEXP; ++ee) {
            unsigned long long m = __ballot(e == ee);
            if (e == ee && lane == (__ffsll((long long)m) - 1))
                atomicAdd(&hist[ee], __popcll(m));
        }
    }
    __syncthreads();
    if (tid == 0) {
        int s = 0;
        for (int e = 0; e < NEXP; ++e) {
            cursor[e] = s;
            ws_i[e] = hist[e];
            ws_i[16 + e] = s;
            s += hist[e];
        }
        ws_i[16 + NEXP] = s;
    }
    __syncthreads();
    for (int i = tid; i < T_TOK; i += 1024) {
        int e = pos[i];
        int p = 0;
        #pragma unroll
        for (int ee = 0; ee < NEXP; ++ee) {
            unsigned long long m = __ballot(e == ee);
            if (e == ee) {
                int leader = __ffsll((long long)m) - 1;
                int rank = __popcll(m & ((1ull << lane) - 1ull));
                int base = 0;
                if (lane == leader) base = atomicAdd(&cursor[ee], __popcll(m));
                base = __shfl(base, leader);
                p = base + rank;
            }
        }
        perm[p] = i;
    }
}

// gather + fp32->bf16 (sorted order)
__global__ void k_gather(const float* __restrict__ x, const int* __restrict__ perm,
                         unsigned short* __restrict__ xg) {
    int p = blockIdx.x;
    int tok = perm[p];
    int j = threadIdx.x * 4;
    const float4 v = *reinterpret_cast<const float4*>(x + (size_t)tok * DDIM + j);
    uint2 o;
    o.x = cvt2(v.x, v.y);
    o.y = cvt2(v.z, v.w);
    *reinterpret_cast<uint2*>(xg + (size_t)p * DDIM + j) = o;
}

// streaming fp32 -> bf16 conversion of all three weight tensors
__global__ void k_wconv(const float* __restrict__ g, const float* __restrict__ u,
                        const float* __restrict__ d,
                        unsigned short* __restrict__ wg,
                        unsigned short* __restrict__ wu,
                        unsigned short* __restrict__ wd) {
    const int C = NEXP * IDIM * DDIM / 4;   // float4 count per tensor = 3145728
    for (int i = blockIdx.x * blockDim.x + threadIdx.x; i < 3 * C;
         i += gridDim.x * blockDim.x) {
        const float* src; unsigned short* dst; int off;
        if (i < C)          { src = g; dst = wg; off = i; }
        else if (i < 2 * C) { src = u; dst = wu; off = i - C; }
        else                { src = d; dst = wd; off = i - 2 * C; }
        float4 v = reinterpret_cast<const float4*>(src)[off];
        uint2 o;
        o.x = cvt2(v.x, v.y);
        o.y = cvt2(v.z, v.w);
        reinterpret_cast<uint2*>(dst)[off] = o;
    }
}

// GEMM1: xg[cnt x 768] @ {gate,up}^T (bf16) -> h = silu(g)*u -> hg bf16
// block: (nt = 64-wide I-tile, mt = 128-token tile, e). 128x128 combined tile:
// B rows 0..63 = gate[nt*64..], 64..127 = up[nt*64..]. waves: wm=wave&1 m-half,
// wsel=wave>>1 matrix. Epilogue: up-waves stash U in LDS, gate-waves fuse silu.
__launch_bounds__(256, 2)
__global__ void k_gemm1(const unsigned short* __restrict__ xg,
                        const unsigned short* __restrict__ wg,
                        const unsigned short* __restrict__ wu,
                        unsigned short* __restrict__ hg,
                        const int* __restrict__ ws_i) {
    const int e   = blockIdx.z;
    const int cnt = ws_i[e];
    const int m0  = blockIdx.y * 128;
    if (cnt == 0 || m0 >= cnt) return;
    const int off = ws_i[16 + e];
    const int nt  = blockIdx.x;          // 0..31

    __shared__ __align__(16) unsigned char smem[32768];
    unsigned short* lsA = (unsigned short*)smem;            // [128][32] bf16, 8KB
    unsigned short* lsB = (unsigned short*)(smem + 8192);   // [128][32]: 0-63 gate, 64-127 up
    float*          lsX = (float*)smem;                     // epilogue 128x64 f32 (32KB)

    const int tid  = threadIdx.x;
    const int lane = tid & 63;
    const int wave = tid >> 6;
    const int wm   = wave & 1;
    const int wsel = wave >> 1;          // 0 = gate, 1 = up

    const int arow = tid >> 2;           // 0..63 (i=0), +64 (i=1)
    const int aq   = tid & 3;

    const unsigned short* gA0 = xg + (size_t)(off + m0 + arow) * DDIM + aq * 8;
    const unsigned short* gA1 = gA0 + (size_t)64 * DDIM;
    const unsigned short* gB0 = wg + ((size_t)e * IDIM + nt * 64 + arow) * DDIM + aq * 8;
    const unsigned short* gB1 = wu + ((size_t)e * IDIM + nt * 64 + arow) * DDIM + aq * 8;
    unsigned short* lA0 = lsA + tid * 8;          // chunk = tid      -> lane*16B packing
    unsigned short* lA1 = lsA + 2048 + tid * 8;   // chunk = 256+tid
    unsigned short* lB0 = lsB + tid * 8;
    unsigned short* lB1 = lsB + 2048 + tid * 8;

    ffrag acc[4][4];
    const ffrag fz = {0.f, 0.f, 0.f, 0.f};
    #pragma unroll
    for (int mi = 0; mi < 4; ++mi)
        #pragma unroll
        for (int ni = 0; ni < 4; ++ni) acc[mi][ni] = fz;

    const int koff = (lane >> 4) * 8;
    const int rsel = lane & 15;

    for (int kt = 0; kt < DDIM / 32; ++kt) {
        const int kb = kt * 32;
        GL2LDS(gA0 + kb, lA0);
        GL2LDS(gA1 + kb, lA1);
        GL2LDS(gB0 + kb, lB0);
        GL2LDS(gB1 + kb, lB1);
        __syncthreads();

        bfrag a[4], b[4];
        #pragma unroll
        for (int mi = 0; mi < 4; ++mi)
            a[mi] = *reinterpret_cast<const bfrag*>(&lsA[(wm * 64 + mi * 16 + rsel) * 32 + koff]);
        #pragma unroll
        for (int ni = 0; ni < 4; ++ni)
            b[ni] = *reinterpret_cast<const bfrag*>(&lsB[(wsel * 64 + ni * 16 + rsel) * 32 + koff]);
        #pragma unroll
        for (int mi = 0; mi < 4; ++mi)
            #pragma unroll
            for (int ni = 0; ni < 4; ++ni)
                acc[mi][ni] = __builtin_amdgcn_mfma_f32_16x16x32_bf16(a[mi], b[ni], acc[mi][ni], 0, 0, 0);
        __syncthreads();
    }

    const int colb  = lane & 15;
    const int rquad = (lane >> 4) * 4;
    if (wsel == 1) {     // up waves: stash U (rows wm*64.., all 64 cols)
        #pragma unroll
        for (int mi = 0; mi < 4; ++mi)
            #pragma unroll
            for (int ni = 0; ni < 4; ++ni)
                #pragma unroll
                for (int r = 0; r < 4; ++r)
                    lsX[(wm * 64 + mi * 16 + rquad + r) * 64 + ni * 16 + colb] = acc[mi][ni][r];
    }
    __syncthreads();
    if (wsel == 0) {     // gate waves: fuse silu(g)*u, store bf16
        #pragma unroll
        for (int mi = 0; mi < 4; ++mi)
            #pragma unroll
            for (int ni = 0; ni < 4; ++ni)
                #pragma unroll
                for (int r = 0; r < 4; ++r) {
                    int ml = wm * 64 + mi * 16 + rquad + r;
                    if (m0 + ml < cnt) {
                        float gv = acc[mi][ni][r];
                        float uv = lsX[ml * 64 + ni * 16 + colb];
                        float h  = (gv / (1.0f + __expf(-gv))) * uv;
                        hg[(size_t)(off + m0 + ml) * IDIM + nt * 64 + ni * 16 + colb] = f2bf(h);
                    }
                }
    }
}

// GEMM2: hg[cnt x 2048] @ down^T (bf16) -> out fp32, scattered rows, split-K=4
__launch_bounds__(256, 2)
__global__ void k_gemm2(const unsigned short* __restrict__ hg,
                        const unsigned short* __restrict__ wd,
                        float* __restrict__ out,
                        const int* __restrict__ ws_i,
                        const int* __restrict__ perm) {
    const int e   = blockIdx.z & 7;
    const int s   = blockIdx.z >> 3;     // 0..3: K-chunk of 512
    const int cnt = ws_i[e];
    const int m0  = blockIdx.y * 128;
    if (cnt == 0 || m0 >= cnt) return;
    const int off = ws_i[16 + e];
    const int n0  = blockIdx.x * 128;    // 0..5

    __shared__ __align__(16) unsigned char smem[16384];
    unsigned short* lsA = (unsigned short*)smem;            // [128][32]
    unsigned short* lsB = (unsigned short*)(smem + 8192);   // [128][32]

    const int tid  = threadIdx.x;
    const int lane = tid & 63;
    const int wave = tid >> 6;
    const int wm   = wave & 1;
    const int wn   = wave >> 1;

    const int arow = tid >> 2;
    const int aq   = tid & 3;

    const unsigned short* gA0 = hg + (size_t)(off + m0 + arow) * IDIM + s * 512 + aq * 8;
    const unsigned short* gA1 = gA0 + (size_t)64 * IDIM;
    const unsigned short* gB0 = wd + ((size_t)e * DDIM + n0 + arow) * IDIM + s * 512 + aq * 8;
    const unsigned short* gB1 = gB0 + (size_t)64 * IDIM;
    unsigned short* lA0 = lsA + tid * 8;
    unsigned short* lA1 = lsA + 2048 + tid * 8;
    unsigned short* lB0 = lsB + tid * 8;
    unsigned short* lB1 = lsB + 2048 + tid * 8;

    ffrag acc[4][4];
    const ffrag fz = {0.f, 0.f, 0.f, 0.f};
    #pragma unroll
    for (int mi = 0; mi < 4; ++mi)
        #pragma unroll
        for (int ni = 0; ni < 4; ++ni) acc[mi][ni] = fz;

    const int koff = (lane >> 4) * 8;
    const int rsel = lane & 15;

    for (int kt = 0; kt < 16; ++kt) {
        const int kb = kt * 32;
        GL2LDS(gA0 + kb, lA0);
        GL2LDS(gA1 + kb, lA1);
        GL2LDS(gB0 + kb, lB0);
        GL2LDS(gB1 + kb, lB1);
        __syncthreads();

        bfrag a[4], b[4];
        #pragma unroll
        for (int mi = 0; mi < 4; ++mi)
            a[mi] = *reinterpret_cast<const bfrag*>(&lsA[(wm * 64 + mi * 16 + rsel) * 32 + koff]);
        #pragma unroll
        for (int ni = 0; ni < 4; ++ni)
            b[ni] = *reinterpret_cast<const bfrag*>(&lsB[(wn * 64 + ni * 16 + rsel) * 32 + koff]);
        #pragma unroll
        for (int mi = 0; mi < 4; ++mi)
            #pragma unroll
            for (int ni = 0; ni < 4; ++ni)
                acc[mi][ni] = __builtin_amdgcn_mfma_f32_16x16x32_bf16(a[mi], b[ni], acc[mi][ni], 0, 0, 0);
        __syncthreads();
    }

    const int colb  = lane & 15;
    const int rquad = (lane >> 4) * 4;
    #pragma unroll
    for (int mi = 0; mi < 4; ++mi)
        #pragma unroll
        for (int r = 0; r < 4; ++r) {
            int ml = wm * 64 + mi * 16 + rquad + r;
            if (m0 + ml < cnt) {
                int tok = perm[off + m0 + ml];
                float* orow = out + (size_t)tok * DDIM + n0 + wn * 64 + colb;
                #pragma unroll
                for (int ni = 0; ni < 4; ++ni)
                    unsafeAtomicAdd(orow + ni * 16, acc[mi][ni][r]);
            }
        }
}

extern "C" void kernel_launch(void* const* d_in, const int* in_sizes, int n_in,
                              void* d_out, int out_size, void* d_ws, size_t ws_size,
                              hipStream_t stream) {
    const float* x      = (const float*)d_in[0];
    const int*   pos    = (const int*)d_in[1];
    const float* gate_w = (const float*)d_in[3];
    const float* up_w   = (const float*)d_in[4];
    const float* down_w = (const float*)d_in[5];
    float* out = (float*)d_out;

    char* ws = (char*)d_ws;
    int* ws_i = (int*)ws;
    int* perm = (int*)(ws + 1024);
    unsigned short* xg = (unsigned short*)(ws + 32768);           // 6.29 MB
    unsigned short* hg = (unsigned short*)(ws + (8ull  << 20));   // 16.78 MB
    unsigned short* wg = (unsigned short*)(ws + (26ull << 20));   // 25.17 MB
    unsigned short* wu = (unsigned short*)(ws + (52ull << 20));   // 25.17 MB
    unsigned short* wd = (unsigned short*)(ws + (78ull << 20));   // 25.17 MB

    (void)hipMemsetAsync(d_out, 0, (size_t)out_size * sizeof(float), stream);
    k_sort<<<dim3(1), dim3(1024), 0, stream>>>(pos, ws_i, perm);
    k_gather<<<dim3(T_TOK), dim3(192), 0, stream>>>(x, perm, xg);
    k_wconv<<<dim3(3072), dim3(256), 0, stream>>>(gate_w, up_w, down_w, wg, wu, wd);

    dim3 g1(IDIM / 64, 32, NEXP);        // (nt, mt-slot, e) ~1024 active
    k_gemm1<<<g1, dim3(256), 0, stream>>>(xg, wg, wu, hg, ws_i);
    dim3 g2(DDIM / 128, 32, NEXP * 4);   // (nt, mt-slot, e|split<<3) ~768 active
    k_gemm2<<<g2, dim3(256), 0, stream>>>(hg, wd, out, ws_i, perm);
}